// Round 3
// baseline (12976.854 us; speedup 1.0000x reference)
//
#include <hip/hip_runtime.h>

// LightGCN propagation: ego = concat(user,item); 3x { ego = A@ego; acc += ego }
// Round-5 (= round-4 design + LDS-OOB hardening after container failure):
//  - k_bscatter: tile-staged LDS multisplit -> coalesced bucket-sorted u64 staging
//  - k_bsort: per-bucket col-chunk (col>>13) counting sort, LDS-staged coalesced out
//  - k_spmm_b: one wg per bucket, 147x64 f32 LDS accumulator, ds_add_f32 accum
//  - every LDS-indexed write is clamped/guarded: bad input degrades to wrong data,
//    never an OOB LDS write (which kills the HSA queue -> container failure).
// Staging (102.4MB) aliases acc+ego1 (dead after k_bsort): T0_NEED = 193.6MB.

typedef unsigned short u16;
typedef unsigned int   u32;
typedef unsigned long long u64;

#define USER_ELEMS   (200000 * 64)
#define N_NODES      300000
#define EMB          64
#define NNZ          12800000
#define TOTAL_ELEMS  (N_NODES * EMB)     // 19,200,000

// ---- T0 bucket geometry ----
#define NBUCK    2048
#define ROWS_PB  147                     // 2048*147 = 301,056 >= 300,000
#define EPB      65536                   // edges per block in A passes
#define NB_A     196                     // ceil(NNZ / EPB)
#define CNT_LEN  (NBUCK * NB_A)          // 401,408
#define TILE     4096
#define NTILES   (EPB / TILE)            // 16
#define CCBITS   13                      // col chunk = col >> 13 (37 chunks)
#define BCAP     6784                    // bucket LDS capacity (mean 6272)

// workspace region sizes (bytes)
#define FLAGS_SZ   256ULL
#define ACC_SZ     76800000ULL           // fp32 acc
#define EGO_SZ     38400000ULL           // bf16 ego
#define RP_SZ      1200128ULL            // row_ptr (T2 fallback)
#define BS_SZ      1024ULL
#define CNTM_SZ    1605632ULL            // CNT_LEN * 4
#define COL_SZ     51200000ULL           // u32 (rl<<19|col) per edge
#define VALSORT_SZ 25600000ULL           // bf16 val per edge
#define BIG_SZ     115200000ULL          // max(stage u64 102.4M, acc+ego1 115.2M)
#define PERM_SZ    51200000ULL
#define LAYER_SZ   76800000ULL

#define T0_NEED (FLAGS_SZ + CNTM_SZ + 2*BS_SZ + COL_SZ + VALSORT_SZ + BIG_SZ)  // 193,607,936
#define T2_NEED (FLAGS_SZ + ACC_SZ + EGO_SZ + 2*RP_SZ + 2*BS_SZ + PERM_SZ)     // 168,802,560

__device__ __forceinline__ float bf2f(u16 b) {
    return __uint_as_float(((u32)b) << 16);
}
__device__ __forceinline__ u16 f2bf(float f) {
    u32 u = __float_as_uint(f);
    u32 r = (u + 0x7fffu + ((u >> 16) & 1u)) >> 16;   // round-to-nearest-even
    return (u16)r;
}

// ---------------- dtype detection ----------------
__global__ void k_detect(const u16* __restrict__ emb, const u16* __restrict__ vals,
                         int* __restrict__ flags) {
    int lane = threadIdx.x;                 // 64 threads, 1 wave
    u16 a = emb[lane * 2];
    int ea = (a >> 7) & 0xFF;
    bool pa = (ea >= 0x60 && ea <= 0x7E);
    unsigned long long ba = __ballot(pa);
    u16 b = vals[lane * 2];
    int eb = (b >> 7) & 0xFF;
    bool pb = (eb >= 0x60 && eb <= 0x7E);
    unsigned long long bb = __ballot(pb);
    if (lane == 0) {
        flags[0] = (__popcll(ba) >= 56) ? 0 : 1;   // 0 = bf16, 1 = fp32
        flags[1] = (__popcll(bb) >= 56) ? 0 : 1;
    }
}

// ---------------- init: ego0 (bf16) + acc (fp32) ----------------
__global__ void k_init(const void* __restrict__ user, const void* __restrict__ item,
                       const int* __restrict__ flags,
                       u16* __restrict__ ego, float* __restrict__ acc) {
    int t = blockIdx.x * blockDim.x + threadIdx.x;
    int e = t * 4;
    if (e >= TOTAL_ELEMS) return;
    float4 f;
    if (flags[0]) {
        const float* src = (e < USER_ELEMS) ? ((const float*)user + e)
                                            : ((const float*)item + (e - USER_ELEMS));
        f = *(const float4*)src;
    } else {
        const u16* src = (e < USER_ELEMS) ? ((const u16*)user + e)
                                          : ((const u16*)item + (e - USER_ELEMS));
        ushort4 v = *(const ushort4*)src;
        f.x = bf2f(v.x); f.y = bf2f(v.y); f.z = bf2f(v.z); f.w = bf2f(v.w);
    }
    ushort4 o;
    o.x = f2bf(f.x); o.y = f2bf(f.y); o.z = f2bf(f.z); o.w = f2bf(f.w);
    *(ushort4*)(ego + e) = o;
    *(float4*)(acc + e) = f;
}

// ---------------- generic 3-phase exclusive scan (EPT = elems/thread) ----------------
template<int EPT>
__global__ void k_scan_reduce(const int* __restrict__ cnt, int* __restrict__ blockSums,
                              int n) {
    __shared__ int s[256];
    int b = blockIdx.x;
    int base = b * (EPT * 256) + threadIdx.x;
    int sum = 0;
#pragma unroll
    for (int k = 0; k < EPT; ++k) {
        int i = base + k * 256;
        if (i < n) sum += cnt[i];
    }
    s[threadIdx.x] = sum;
    __syncthreads();
    for (int off = 128; off > 0; off >>= 1) {
        if (threadIdx.x < (unsigned)off) s[threadIdx.x] += s[threadIdx.x + off];
        __syncthreads();
    }
    if (threadIdx.x == 0) blockSums[b] = s[0];
}

__global__ void k_scan_block(const int* __restrict__ blockSums, int* __restrict__ blockOffs,
                             int nb) {
    __shared__ int s[256];
    int x = (threadIdx.x < nb) ? blockSums[threadIdx.x] : 0;
    s[threadIdx.x] = x;
    __syncthreads();
    for (int off = 1; off < 256; off <<= 1) {
        int t = 0;
        if (threadIdx.x >= (unsigned)off) t = s[threadIdx.x - off];
        __syncthreads();
        s[threadIdx.x] += t;
        __syncthreads();
    }
    if (threadIdx.x < nb) blockOffs[threadIdx.x] = s[threadIdx.x] - x;
}

// In-place safe. cursor2 may be null; may alias cnt.
template<int EPT>
__global__ void k_scan_down(const int* cnt, const int* __restrict__ blockOffs,
                            int* __restrict__ out, int* cursor2,
                            int n, int total, int writeTotal) {
    __shared__ int s[256];
    int b = blockIdx.x;
    int base = b * (EPT * 256) + threadIdx.x * EPT;
    int v[EPT];
    int tsum = 0;
#pragma unroll
    for (int k = 0; k < EPT; ++k) {
        int i = base + k;
        v[k] = (i < n) ? cnt[i] : 0;
        tsum += v[k];
    }
    s[threadIdx.x] = tsum;
    __syncthreads();
    for (int off = 1; off < 256; off <<= 1) {
        int t = 0;
        if (threadIdx.x >= (unsigned)off) t = s[threadIdx.x - off];
        __syncthreads();
        s[threadIdx.x] += t;
        __syncthreads();
    }
    int running = blockOffs[b] + (s[threadIdx.x] - tsum);
#pragma unroll
    for (int k = 0; k < EPT; ++k) {
        int i = base + k;
        if (i < n) {
            out[i] = running;
            if (cursor2) cursor2[i] = running;
        }
        running += v[k];
    }
    if (writeTotal && b == 0 && threadIdx.x == 0) out[n] = total;
}

// ---------------- A1: per-block bucket histogram ----------------
__global__ void __launch_bounds__(512) k_bhist(const int* __restrict__ rows,
                                               int* __restrict__ counts) {
    __shared__ int c[NBUCK];
    for (int i = threadIdx.x; i < NBUCK; i += 512) c[i] = 0;
    __syncthreads();
    int b0 = blockIdx.x * EPB;
    for (int i = threadIdx.x; i < EPB; i += 512) {
        int e = b0 + i;
        if (e < NNZ) {
            u32 k = (u32)rows[e] / ROWS_PB;
            if (k >= NBUCK) k = NBUCK - 1;          // guard: bad row -> clamp
            atomicAdd(&c[k], 1);
        }
    }
    __syncthreads();
    for (int k = threadIdx.x; k < NBUCK; k += 512)
        counts[k * NB_A + blockIdx.x] = c[k];
}

// ---------------- A3: tile-staged multisplit scatter ----------------
// Per 4096-edge tile: LDS hist -> LDS scan -> place bucket-sorted in LDS ->
// coalesced copy-out. Each (block,bucket) chunk ~1 cache line, completed by
// one block (same XCD L2) across tiles.
__global__ void __launch_bounds__(512) k_bscatter(
    const int* __restrict__ rows, const int* __restrict__ cols,
    const void* __restrict__ vals, const int* __restrict__ flags,
    const int* __restrict__ offs, u64* __restrict__ stg) {
    __shared__ int h[NBUCK];        // 8KB  per-tile bucket counts
    __shared__ u16 o[NBUCK];        // 4KB  inclusive scan of h (<=4096 fits u16)
    __shared__ int gbase[NBUCK];    // 8KB  running global write base per bucket
    __shared__ u64 st[TILE];        // 32KB staged payloads
    __shared__ u16 kst[TILE];       // 8KB  staged bucket ids      (total 60KB)
    int b = blockIdx.x, tid = threadIdx.x;
    for (int i = tid; i < NBUCK; i += 512) gbase[i] = offs[i * NB_A + b];
    int valF32 = flags[1];
    for (int t = 0; t < NTILES; ++t) {
        for (int i = tid; i < NBUCK; i += 512) h[i] = 0;
        __syncthreads();
        int ebase = b * EPB + t * TILE;
        int kk[8]; int rk[8]; u64 pl[8];
#pragma unroll
        for (int j = 0; j < 8; ++j) {
            int e = ebase + tid + j * 512;
            kk[j] = -1;
            if (e < NNZ) {
                u32 r = (u32)rows[e];
                u32 c = (u32)cols[e] & 0x7FFFFu;     // guard: 19-bit col
                u16 v = valF32 ? f2bf(((const float*)vals)[e]) : ((const u16*)vals)[e];
                u32 k = r / ROWS_PB;
                if (k >= NBUCK) k = NBUCK - 1;       // guard: bad row -> clamp
                u32 rl = r - k * ROWS_PB;
                if (rl >= ROWS_PB) rl = ROWS_PB - 1; // guard
                kk[j] = (int)k;
                pl[j] = ((u64)v << 32) | (u64)((rl << 19) | c);
                rk[j] = atomicAdd(&h[k], 1);
            }
        }
        __syncthreads();
        for (int i = tid; i < NBUCK; i += 512) o[i] = (u16)h[i];
        __syncthreads();
        for (int off = 1; off < NBUCK; off <<= 1) {   // Hillis-Steele inclusive
            u16 t0[4];
#pragma unroll
            for (int q = 0; q < 4; ++q) {
                int i = tid + q * 512;
                t0[q] = (i >= off) ? o[i - off] : (u16)0;
            }
            __syncthreads();
#pragma unroll
            for (int q = 0; q < 4; ++q) o[tid + q * 512] += t0[q];
            __syncthreads();
        }
#pragma unroll
        for (int j = 0; j < 8; ++j) {
            if (kk[j] >= 0) {
                int excl = (int)o[kk[j]] - h[kk[j]];
                int p = excl + rk[j];
                if (p >= 0 && p < TILE) {            // guard: never OOB LDS
                    st[p] = pl[j];
                    kst[p] = (u16)kk[j];
                }
            }
        }
        __syncthreads();
        int cnt = (int)o[NBUCK - 1];
        if (cnt > TILE) cnt = TILE;                  // guard
        for (int i = tid; i < cnt; i += 512) {
            int k = kst[i];
            int excl = (int)o[k] - h[k];
            long long p = (long long)gbase[k] + (i - excl);
            if (p >= 0 && p < NNZ) stg[p] = st[i];   // guard: never OOB global
        }
        __syncthreads();
        for (int i = tid; i < NBUCK; i += 512) gbase[i] += h[i];
        __syncthreads();
    }
}

// ---------------- B: per-bucket col-chunk counting sort, coalesced output -------
__global__ void __launch_bounds__(512) k_bsort(
    const int* __restrict__ offs, const u64* __restrict__ stg,
    int* __restrict__ col_s, u16* __restrict__ val_s) {
    __shared__ int h[64], oo[64], rk[64];
    __shared__ u32 lcol[BCAP];          // 27,136B
    __shared__ u16 lval[BCAP];          // 13,568B  (total ~41.5KB)
    int k = blockIdx.x, tid = threadIdx.x;
    int s = offs[k * NB_A];
    int e = (k == NBUCK - 1) ? NNZ : offs[(k + 1) * NB_A];
    if (e > NNZ) e = NNZ;                            // guard
    if (s < 0) s = 0;                                // guard
    if (tid < 64) h[tid] = 0;
    __syncthreads();
    for (int j = s + tid; j < e; j += 512) {
        u32 lo = (u32)stg[j];
        atomicAdd(&h[((lo & 0x7FFFFu) >> CCBITS) & 63], 1);
    }
    __syncthreads();
    if (tid == 0) {
        int run = 0;
        for (int q = 0; q < 64; ++q) { oo[q] = run; run += h[q]; }
    }
    __syncthreads();
    if (tid < 64) rk[tid] = oo[tid];
    __syncthreads();
    int n = e - s;
    for (int j = s + tid; j < e; j += 512) {
        u64 pk = stg[j];
        u32 lo = (u32)pk;
        int cc = (int)(((lo & 0x7FFFFu) >> CCBITS) & 63);
        int p = atomicAdd(&rk[cc], 1);
        if (p >= 0 && p < BCAP) { lcol[p] = lo; lval[p] = (u16)(pk >> 32); }
        else if (p >= 0 && p < n) {                  // overflow fallback, guarded
            col_s[s + p] = (int)lo; val_s[s + p] = (u16)(pk >> 32);
        }
    }
    __syncthreads();
    int m = n < BCAP ? n : BCAP;
    for (int i = tid; i < m; i += 512) {
        col_s[s + i] = (int)lcol[i];
        val_s[s + i] = lval[i];
    }
}

// ---------------- SpMM: one wg per bucket, LDS f32 accumulator ----------------
__global__ void __launch_bounds__(512) k_spmm_b(
    const int* __restrict__ offs, const int* __restrict__ col_s,
    const u16* __restrict__ val_s, const u16* __restrict__ ego_in,
    u16* __restrict__ ego_out, float* __restrict__ acc) {
    __shared__ float lacc[ROWS_PB * EMB];   // 37,632B -> 4 wg/CU
    int k = blockIdx.x, tid = threadIdx.x;
    for (int i = tid; i < ROWS_PB * EMB; i += 512) lacc[i] = 0.f;
    __syncthreads();
    int s = offs[k * NB_A];
    int e = (k == NBUCK - 1) ? NNZ : offs[(k + 1) * NB_A];
    if (e > NNZ) e = NNZ;                            // guard
    if (s < 0) s = 0;                                // guard
    int lane = tid & 63, w = tid >> 6;      // 8 waves, lane = emb dim
    for (int j0 = s + w * 8; j0 < e; j0 += 64) {
#pragma unroll
        for (int q = 0; q < 8; ++q) {
            int j = j0 + q;
            if (j < e) {
                u32 cs = (u32)col_s[j];
                float wv = bf2f(val_s[j]);
                u32 c = cs & 0x7FFFFu;
                if (c >= N_NODES) c = N_NODES - 1;   // guard
                u32 rl = cs >> 19;
                if (rl >= ROWS_PB) rl = ROWS_PB - 1; // guard: never OOB LDS
                float x = bf2f(ego_in[c * EMB + lane]);
                atomicAdd(&lacc[rl * EMB + lane], wv * x);
            }
        }
    }
    __syncthreads();
    int rbase = k * ROWS_PB;
    for (int i = tid; i < ROWS_PB * EMB; i += 512) {
        int r = rbase + (i >> 6);
        if (r < N_NODES) {
            int oidx = r * EMB + (i & 63);
            acc[oidx] += lacc[i];
            ego_out[oidx] = f2bf(lacc[i]);
        }
    }
}

// ---------------- T2 fallback: CSR by permutation ----------------
__global__ void k_hist(const int* __restrict__ rows, int* __restrict__ cnt) {
    int e = blockIdx.x * blockDim.x + threadIdx.x;
    if (e < NNZ) atomicAdd(&cnt[rows[e]], 1);
}

__global__ void k_scatter_perm(const int* __restrict__ rows, int* __restrict__ cursor,
                               u32* __restrict__ perm) {
    int e = blockIdx.x * blockDim.x + threadIdx.x;
    if (e >= NNZ) return;
    int r = rows[e];
    int p = atomicAdd(&cursor[r], 1);
    perm[p] = (u32)e;
}

__global__ void __launch_bounds__(256) k_spmm_perm(
    const int* __restrict__ row_ptr, const u32* __restrict__ perm,
    const int* __restrict__ cols, const void* __restrict__ vals,
    const int* __restrict__ flags, const u16* __restrict__ ego_in,
    u16* __restrict__ ego_out, float* __restrict__ acc) {
    int row = __builtin_amdgcn_readfirstlane(
        (int)((blockIdx.x * blockDim.x + threadIdx.x) >> 6));
    int lane = threadIdx.x & 63;
    if (row >= N_NODES) return;
    int valF32 = flags[1];
    int start = row_ptr[row];
    int end   = row_ptr[row + 1];
    float a = 0.f;
    for (int j = start; j < end; ++j) {
        u32 eid = perm[j];
        int c = cols[eid];
        float w = valF32 ? ((const float*)vals)[eid] : bf2f(((const u16*)vals)[eid]);
        a += w * bf2f(ego_in[c * EMB + lane]);
    }
    int o = row * EMB + lane;
    acc[o] += a;
    ego_out[o] = f2bf(a);
}

// ---------------- T3 fallback: edge-parallel atomics ----------------
__global__ void __launch_bounds__(256) k_edge_atomic(
    const int* __restrict__ rows, const int* __restrict__ cols,
    const void* __restrict__ vals, const int* __restrict__ flags,
    const u16* __restrict__ ego, float* __restrict__ layer) {
    int t = blockIdx.x * blockDim.x + threadIdx.x;
    int e = t >> 4;
    if (e >= NNZ) return;
    int d4 = (t & 15) * 4;
    int r = rows[e], c = cols[e];
    float w = flags[1] ? ((const float*)vals)[e] : bf2f(((const u16*)vals)[e]);
    ushort4 x = *(const ushort4*)(ego + c * EMB + d4);
    float* dst = layer + r * EMB + d4;
    atomicAdd(dst + 0, w * bf2f(x.x));
    atomicAdd(dst + 1, w * bf2f(x.y));
    atomicAdd(dst + 2, w * bf2f(x.z));
    atomicAdd(dst + 3, w * bf2f(x.w));
}

__global__ void k_layer_fin(float* __restrict__ layer, float* __restrict__ acc,
                            u16* __restrict__ ego) {
    int t = blockIdx.x * blockDim.x + threadIdx.x;
    int e = t * 4;
    if (e >= TOTAL_ELEMS) return;
    float4 L = *(const float4*)(layer + e);
    float4 A = *(const float4*)(acc + e);
    A.x += L.x; A.y += L.y; A.z += L.z; A.w += L.w;
    *(float4*)(acc + e) = A;
    ushort4 o;
    o.x = f2bf(L.x); o.y = f2bf(L.y); o.z = f2bf(L.z); o.w = f2bf(L.w);
    *(ushort4*)(ego + e) = o;
    float4 z; z.x = 0.f; z.y = 0.f; z.z = 0.f; z.w = 0.f;
    *(float4*)(layer + e) = z;
}

// ---------------- finalize: out = (acc / 4) in output dtype ----------------
__global__ void k_final(const float* __restrict__ acc, const int* __restrict__ flags,
                        void* __restrict__ out) {
    int t = blockIdx.x * blockDim.x + threadIdx.x;
    int e = t * 4;
    if (e >= TOTAL_ELEMS) return;
    float4 f = *(const float4*)(acc + e);
    f.x *= 0.25f; f.y *= 0.25f; f.z *= 0.25f; f.w *= 0.25f;
    if (flags[0]) {
        *(float4*)((float*)out + e) = f;
    } else {
        ushort4 v;
        v.x = f2bf(f.x); v.y = f2bf(f.y); v.z = f2bf(f.z); v.w = f2bf(f.w);
        *(ushort4*)((u16*)out + e) = v;
    }
}

extern "C" void kernel_launch(void* const* d_in, const int* in_sizes, int n_in,
                              void* d_out, int out_size, void* d_ws, size_t ws_size,
                              hipStream_t stream) {
    const void* user = d_in[0];
    const void* item = d_in[1];
    const void* vals = d_in[2];
    const int*  rows = (const int*)d_in[3];
    const int*  cols = (const int*)d_in[4];

    char* ws = (char*)d_ws;
    int* flags = (int*)ws;

    const int initGrid = (TOTAL_ELEMS / 4 + 255) / 256;   // 18750
    const int edgeGrid = (NNZ + 255) / 256;                // 50000
    const int spmmGrid = (N_NODES * 64) / 256;             // 75000

    k_detect<<<1, 64, 0, stream>>>((const u16*)user, (const u16*)vals, flags);

    if (ws_size >= T0_NEED) {
        // ---- T0: bucketed multisplit + col-chunk sort + LDS-accumulator SpMM ----
        size_t off = FLAGS_SZ;
        int* cntm = (int*)(ws + off); off += CNTM_SZ;     // counts -> offsets (in place)
        int* bs2  = (int*)(ws + off); off += BS_SZ;
        int* bo2  = (int*)(ws + off); off += BS_SZ;
        int* col_s = (int*)(ws + off); off += COL_SZ;     // (rl<<19)|col
        u16* val_s = (u16*)(ws + off); off += VALSORT_SZ;
        char* big  = ws + off;                            // 115.2MB shared region
        u64*   stg = (u64*)big;                           // staging (dead after k_bsort)
        float* acc = (float*)big;                         // live after k_init
        u16 *ego0, *ego1;
        bool outF32 = (out_size >= (int)(TOTAL_ELEMS * 4));
        if (outF32) {                                     // both egos fit in d_out
            ego0 = (u16*)d_out;
            ego1 = (u16*)d_out + TOTAL_ELEMS;
        } else {
            ego0 = (u16*)d_out;
            ego1 = (u16*)(big + ACC_SZ);
        }

        k_bhist<<<NB_A, 512, 0, stream>>>(rows, cntm);
        // k-major exclusive scan of the 2048 x 196 count matrix (in place)
        k_scan_reduce<16><<<98, 256, 0, stream>>>(cntm, bs2, CNT_LEN);
        k_scan_block<<<1, 256, 0, stream>>>(bs2, bo2, 98);
        k_scan_down<16><<<98, 256, 0, stream>>>(cntm, bo2, cntm, (int*)0, CNT_LEN, 0, 0);

        k_bscatter<<<NB_A, 512, 0, stream>>>(rows, cols, vals, flags, cntm, stg);
        k_bsort<<<NBUCK, 512, 0, stream>>>(cntm, stg, col_s, val_s);

        k_init<<<initGrid, 256, 0, stream>>>(user, item, flags, ego0, acc); // after k_bsort: acc aliases staging
        k_spmm_b<<<NBUCK, 512, 0, stream>>>(cntm, col_s, val_s, ego0, ego1, acc);
        k_spmm_b<<<NBUCK, 512, 0, stream>>>(cntm, col_s, val_s, ego1, ego0, acc);
        k_spmm_b<<<NBUCK, 512, 0, stream>>>(cntm, col_s, val_s, ego0, ego1, acc);
        k_final<<<initGrid, 256, 0, stream>>>(acc, flags, d_out);
    } else if (ws_size >= T2_NEED) {
        // ---- T2: permutation CSR ----
        size_t off = FLAGS_SZ;
        float* acc = (float*)(ws + off); off += ACC_SZ;
        u16* ego0 = (u16*)d_out;
        u16* ego1 = (u16*)(ws + off); off += EGO_SZ;
        int* row_ptr = (int*)(ws + off); off += RP_SZ;
        int* cursor  = (int*)(ws + off); off += RP_SZ;
        int* bsums   = (int*)(ws + off); off += BS_SZ;
        int* boffs   = (int*)(ws + off); off += BS_SZ;
        u32* perm    = (u32*)(ws + off); off += PERM_SZ;

        hipMemsetAsync(cursor, 0, N_NODES * sizeof(int), stream);
        k_init<<<initGrid, 256, 0, stream>>>(user, item, flags, ego0, acc);
        k_hist<<<edgeGrid, 256, 0, stream>>>(rows, cursor);
        k_scan_reduce<8><<<147, 256, 0, stream>>>(cursor, bsums, N_NODES);
        k_scan_block<<<1, 256, 0, stream>>>(bsums, boffs, 147);
        k_scan_down<8><<<147, 256, 0, stream>>>(cursor, boffs, row_ptr, cursor,
                                                N_NODES, NNZ, 1);
        k_scatter_perm<<<edgeGrid, 256, 0, stream>>>(rows, cursor, perm);
        k_spmm_perm<<<spmmGrid, 256, 0, stream>>>(row_ptr, perm, cols, vals, flags,
                                                  ego0, ego1, acc);
        k_spmm_perm<<<spmmGrid, 256, 0, stream>>>(row_ptr, perm, cols, vals, flags,
                                                  ego1, ego0, acc);
        k_spmm_perm<<<spmmGrid, 256, 0, stream>>>(row_ptr, perm, cols, vals, flags,
                                                  ego0, ego1, acc);
        k_final<<<initGrid, 256, 0, stream>>>(acc, flags, d_out);
    } else {
        // ---- T3: edge-parallel atomics, minimal footprint ----
        size_t off = FLAGS_SZ;
        float* acc   = (float*)(ws + off); off += ACC_SZ;
        float* layer = (float*)(ws + off); off += LAYER_SZ;
        u16* ego = (u16*)d_out;
        hipMemsetAsync(layer, 0, LAYER_SZ, stream);
        k_init<<<initGrid, 256, 0, stream>>>(user, item, flags, ego, acc);
        const int atomGrid = (NNZ * 16) / 256;
        for (int l = 0; l < 3; ++l) {
            k_edge_atomic<<<atomGrid, 256, 0, stream>>>(rows, cols, vals, flags, ego, layer);
            k_layer_fin<<<initGrid, 256, 0, stream>>>(layer, acc, ego);
        }
        k_final<<<initGrid, 256, 0, stream>>>(acc, flags, d_out);
    }
}

// Round 4
// 1376.054 us; speedup vs baseline: 9.4305x; 9.4305x over previous
//
#include <hip/hip_runtime.h>

// LightGCN propagation: ego = concat(user,item); 3x { ego = A@ego; acc += ego }
// Round-6: keep the fast guarded bucket build (bhist -> scans -> tile-multisplit
// bscatter, ~440us total incl. init/final), but:
//  - k_bsort now sorts each bucket BY ROW (147 bins) -> true global CSR order,
//    and emits row_ptr for free (bucket base from offs + local 147-bin scan).
//    Global row-histogram/scan machinery stays deleted.
//  - SpMM reverted to the PROVEN wave-per-row CSR kernel (~470us/layer measured
//    in earlier rounds). Round-5's per-bucket LDS-accumulator SpMM was 9x slower
//    (VGPR=8 -> zero memory-level parallelism, 1 edge per 6400 cyc per wave).
//    Unroll bumped 4 -> 8 for more gathers in flight; col clamped (OOB safety).
// Staging (102.4MB) aliases acc+ego1 (dead after k_bsort). T0_NEED = 194.8MB.

typedef unsigned short u16;
typedef unsigned int   u32;
typedef unsigned long long u64;

#define USER_ELEMS   (200000 * 64)
#define N_NODES      300000
#define EMB          64
#define NNZ          12800000
#define TOTAL_ELEMS  (N_NODES * EMB)     // 19,200,000

// ---- T0 bucket geometry ----
#define NBUCK    2048
#define ROWS_PB  147                     // 2048*147 = 301,056 >= 300,000
#define EPB      65536                   // edges per block in A passes
#define NB_A     196                     // ceil(NNZ / EPB)
#define CNT_LEN  (NBUCK * NB_A)          // 401,408
#define TILE     4096
#define NTILES   (EPB / TILE)            // 16
#define BCAP     6784                    // bucket LDS capacity (mean 6272, +6.5 sigma)

// workspace region sizes (bytes)
#define FLAGS_SZ   256ULL
#define ACC_SZ     76800000ULL           // fp32 acc
#define EGO_SZ     38400000ULL           // bf16 ego
#define RP_SZ      1200128ULL            // row_ptr (300,032 ints)
#define BS_SZ      1024ULL
#define CNTM_SZ    1605632ULL            // CNT_LEN * 4
#define COL_SZ     51200000ULL           // u32 col per edge (CSR)
#define VALSORT_SZ 25600000ULL           // bf16 val per edge (CSR)
#define BIG_SZ     115200000ULL          // max(stage u64 102.4M, acc+ego1 115.2M)
#define PERM_SZ    51200000ULL
#define LAYER_SZ   76800000ULL

#define T0_NEED (FLAGS_SZ + CNTM_SZ + 2*BS_SZ + COL_SZ + VALSORT_SZ + RP_SZ + BIG_SZ) // 194,808,064
#define T2_NEED (FLAGS_SZ + ACC_SZ + EGO_SZ + 2*RP_SZ + 2*BS_SZ + PERM_SZ)            // 168,802,560

__device__ __forceinline__ float bf2f(u16 b) {
    return __uint_as_float(((u32)b) << 16);
}
__device__ __forceinline__ u16 f2bf(float f) {
    u32 u = __float_as_uint(f);
    u32 r = (u + 0x7fffu + ((u >> 16) & 1u)) >> 16;   // round-to-nearest-even
    return (u16)r;
}

// ---------------- dtype detection ----------------
__global__ void k_detect(const u16* __restrict__ emb, const u16* __restrict__ vals,
                         int* __restrict__ flags) {
    int lane = threadIdx.x;                 // 64 threads, 1 wave
    u16 a = emb[lane * 2];
    int ea = (a >> 7) & 0xFF;
    bool pa = (ea >= 0x60 && ea <= 0x7E);
    unsigned long long ba = __ballot(pa);
    u16 b = vals[lane * 2];
    int eb = (b >> 7) & 0xFF;
    bool pb = (eb >= 0x60 && eb <= 0x7E);
    unsigned long long bb = __ballot(pb);
    if (lane == 0) {
        flags[0] = (__popcll(ba) >= 56) ? 0 : 1;   // 0 = bf16, 1 = fp32
        flags[1] = (__popcll(bb) >= 56) ? 0 : 1;
    }
}

// ---------------- init: ego0 (bf16) + acc (fp32) ----------------
__global__ void k_init(const void* __restrict__ user, const void* __restrict__ item,
                       const int* __restrict__ flags,
                       u16* __restrict__ ego, float* __restrict__ acc) {
    int t = blockIdx.x * blockDim.x + threadIdx.x;
    int e = t * 4;
    if (e >= TOTAL_ELEMS) return;
    float4 f;
    if (flags[0]) {
        const float* src = (e < USER_ELEMS) ? ((const float*)user + e)
                                            : ((const float*)item + (e - USER_ELEMS));
        f = *(const float4*)src;
    } else {
        const u16* src = (e < USER_ELEMS) ? ((const u16*)user + e)
                                          : ((const u16*)item + (e - USER_ELEMS));
        ushort4 v = *(const ushort4*)src;
        f.x = bf2f(v.x); f.y = bf2f(v.y); f.z = bf2f(v.z); f.w = bf2f(v.w);
    }
    ushort4 o;
    o.x = f2bf(f.x); o.y = f2bf(f.y); o.z = f2bf(f.z); o.w = f2bf(f.w);
    *(ushort4*)(ego + e) = o;
    *(float4*)(acc + e) = f;
}

// ---------------- generic 3-phase exclusive scan (EPT = elems/thread) ----------------
template<int EPT>
__global__ void k_scan_reduce(const int* __restrict__ cnt, int* __restrict__ blockSums,
                              int n) {
    __shared__ int s[256];
    int b = blockIdx.x;
    int base = b * (EPT * 256) + threadIdx.x;
    int sum = 0;
#pragma unroll
    for (int k = 0; k < EPT; ++k) {
        int i = base + k * 256;
        if (i < n) sum += cnt[i];
    }
    s[threadIdx.x] = sum;
    __syncthreads();
    for (int off = 128; off > 0; off >>= 1) {
        if (threadIdx.x < (unsigned)off) s[threadIdx.x] += s[threadIdx.x + off];
        __syncthreads();
    }
    if (threadIdx.x == 0) blockSums[b] = s[0];
}

__global__ void k_scan_block(const int* __restrict__ blockSums, int* __restrict__ blockOffs,
                             int nb) {
    __shared__ int s[256];
    int x = (threadIdx.x < nb) ? blockSums[threadIdx.x] : 0;
    s[threadIdx.x] = x;
    __syncthreads();
    for (int off = 1; off < 256; off <<= 1) {
        int t = 0;
        if (threadIdx.x >= (unsigned)off) t = s[threadIdx.x - off];
        __syncthreads();
        s[threadIdx.x] += t;
        __syncthreads();
    }
    if (threadIdx.x < nb) blockOffs[threadIdx.x] = s[threadIdx.x] - x;
}

// In-place safe. cursor2 may be null; may alias cnt.
template<int EPT>
__global__ void k_scan_down(const int* cnt, const int* __restrict__ blockOffs,
                            int* __restrict__ out, int* cursor2,
                            int n, int total, int writeTotal) {
    __shared__ int s[256];
    int b = blockIdx.x;
    int base = b * (EPT * 256) + threadIdx.x * EPT;
    int v[EPT];
    int tsum = 0;
#pragma unroll
    for (int k = 0; k < EPT; ++k) {
        int i = base + k;
        v[k] = (i < n) ? cnt[i] : 0;
        tsum += v[k];
    }
    s[threadIdx.x] = tsum;
    __syncthreads();
    for (int off = 1; off < 256; off <<= 1) {
        int t = 0;
        if (threadIdx.x >= (unsigned)off) t = s[threadIdx.x - off];
        __syncthreads();
        s[threadIdx.x] += t;
        __syncthreads();
    }
    int running = blockOffs[b] + (s[threadIdx.x] - tsum);
#pragma unroll
    for (int k = 0; k < EPT; ++k) {
        int i = base + k;
        if (i < n) {
            out[i] = running;
            if (cursor2) cursor2[i] = running;
        }
        running += v[k];
    }
    if (writeTotal && b == 0 && threadIdx.x == 0) out[n] = total;
}

// ---------------- A1: per-block bucket histogram ----------------
__global__ void __launch_bounds__(512) k_bhist(const int* __restrict__ rows,
                                               int* __restrict__ counts) {
    __shared__ int c[NBUCK];
    for (int i = threadIdx.x; i < NBUCK; i += 512) c[i] = 0;
    __syncthreads();
    int b0 = blockIdx.x * EPB;
    for (int i = threadIdx.x; i < EPB; i += 512) {
        int e = b0 + i;
        if (e < NNZ) {
            u32 k = (u32)rows[e] / ROWS_PB;
            if (k >= NBUCK) k = NBUCK - 1;          // guard: bad row -> clamp
            atomicAdd(&c[k], 1);
        }
    }
    __syncthreads();
    for (int k = threadIdx.x; k < NBUCK; k += 512)
        counts[k * NB_A + blockIdx.x] = c[k];
}

// ---------------- A3: tile-staged multisplit scatter ----------------
// Per 4096-edge tile: LDS hist -> LDS scan -> place bucket-sorted in LDS ->
// coalesced copy-out. Each (block,bucket) chunk ~1 cache line, completed by
// one block (same XCD L2) across tiles.
__global__ void __launch_bounds__(512) k_bscatter(
    const int* __restrict__ rows, const int* __restrict__ cols,
    const void* __restrict__ vals, const int* __restrict__ flags,
    const int* __restrict__ offs, u64* __restrict__ stg) {
    __shared__ int h[NBUCK];        // 8KB  per-tile bucket counts
    __shared__ u16 o[NBUCK];        // 4KB  inclusive scan of h (<=4096 fits u16)
    __shared__ int gbase[NBUCK];    // 8KB  running global write base per bucket
    __shared__ u64 st[TILE];        // 32KB staged payloads
    __shared__ u16 kst[TILE];       // 8KB  staged bucket ids      (total 60KB)
    int b = blockIdx.x, tid = threadIdx.x;
    for (int i = tid; i < NBUCK; i += 512) gbase[i] = offs[i * NB_A + b];
    int valF32 = flags[1];
    for (int t = 0; t < NTILES; ++t) {
        for (int i = tid; i < NBUCK; i += 512) h[i] = 0;
        __syncthreads();
        int ebase = b * EPB + t * TILE;
        int kk[8]; int rk[8]; u64 pl[8];
#pragma unroll
        for (int j = 0; j < 8; ++j) {
            int e = ebase + tid + j * 512;
            kk[j] = -1;
            if (e < NNZ) {
                u32 r = (u32)rows[e];
                u32 c = (u32)cols[e] & 0x7FFFFu;     // guard: 19-bit col
                u16 v = valF32 ? f2bf(((const float*)vals)[e]) : ((const u16*)vals)[e];
                u32 k = r / ROWS_PB;
                if (k >= NBUCK) k = NBUCK - 1;       // guard: bad row -> clamp
                u32 rl = r - k * ROWS_PB;
                if (rl >= ROWS_PB) rl = ROWS_PB - 1; // guard
                kk[j] = (int)k;
                pl[j] = ((u64)v << 32) | (u64)((rl << 19) | c);
                rk[j] = atomicAdd(&h[k], 1);
            }
        }
        __syncthreads();
        for (int i = tid; i < NBUCK; i += 512) o[i] = (u16)h[i];
        __syncthreads();
        for (int off = 1; off < NBUCK; off <<= 1) {   // Hillis-Steele inclusive
            u16 t0[4];
#pragma unroll
            for (int q = 0; q < 4; ++q) {
                int i = tid + q * 512;
                t0[q] = (i >= off) ? o[i - off] : (u16)0;
            }
            __syncthreads();
#pragma unroll
            for (int q = 0; q < 4; ++q) o[tid + q * 512] += t0[q];
            __syncthreads();
        }
#pragma unroll
        for (int j = 0; j < 8; ++j) {
            if (kk[j] >= 0) {
                int excl = (int)o[kk[j]] - h[kk[j]];
                int p = excl + rk[j];
                if (p >= 0 && p < TILE) {            // guard: never OOB LDS
                    st[p] = pl[j];
                    kst[p] = (u16)kk[j];
                }
            }
        }
        __syncthreads();
        int cnt = (int)o[NBUCK - 1];
        if (cnt > TILE) cnt = TILE;                  // guard
        for (int i = tid; i < cnt; i += 512) {
            int k = kst[i];
            int excl = (int)o[k] - h[k];
            long long p = (long long)gbase[k] + (i - excl);
            if (p >= 0 && p < NNZ) stg[p] = st[i];   // guard: never OOB global
        }
        __syncthreads();
        for (int i = tid; i < NBUCK; i += 512) gbase[i] += h[i];
        __syncthreads();
    }
}

// ---------------- B: per-bucket ROW sort -> global CSR + row_ptr ----------------
// One wg per bucket. 147-bin LDS histogram + serial scan gives within-bucket row
// offsets; bucket base offs[k*NB_A] makes them global -> row_ptr for free.
// Edges placed in row order in LDS, then written out coalesced.
__global__ void __launch_bounds__(512) k_bsort(
    const int* __restrict__ offs, const u64* __restrict__ stg,
    int* __restrict__ col_s, u16* __restrict__ val_s, int* __restrict__ row_ptr) {
    __shared__ int h[ROWS_PB], ex[ROWS_PB + 1], rk[ROWS_PB];
    __shared__ u32 lcol[BCAP];          // 27,136B
    __shared__ u16 lval[BCAP];          // 13,568B  (total ~42.5KB -> 3 wg/CU)
    int k = blockIdx.x, tid = threadIdx.x;
    int s = offs[k * NB_A];
    int e = (k == NBUCK - 1) ? NNZ : offs[(k + 1) * NB_A];
    if (e > NNZ) e = NNZ;                            // guard
    if (s < 0) s = 0;                                // guard
    for (int i = tid; i < ROWS_PB; i += 512) h[i] = 0;
    __syncthreads();
    for (int j = s + tid; j < e; j += 512) {
        u32 rl = ((u32)stg[j]) >> 19;
        if (rl >= ROWS_PB) rl = ROWS_PB - 1;         // guard (stale staging)
        atomicAdd(&h[rl], 1);
    }
    __syncthreads();
    if (tid == 0) {
        int run = 0;
        for (int q = 0; q < ROWS_PB; ++q) { ex[q] = run; run += h[q]; }
        ex[ROWS_PB] = run;
    }
    __syncthreads();
    for (int i = tid; i < ROWS_PB; i += 512) rk[i] = ex[i];
    __syncthreads();
    int n = e - s;
    for (int j = s + tid; j < e; j += 512) {
        u64 pk = stg[j];
        u32 lo = (u32)pk;
        u32 rl = lo >> 19;
        if (rl >= ROWS_PB) rl = ROWS_PB - 1;         // guard
        int p = atomicAdd(&rk[rl], 1);
        if (p >= 0 && p < BCAP) { lcol[p] = lo & 0x7FFFFu; lval[p] = (u16)(pk >> 32); }
        else if (p >= 0 && p < n) {                  // overflow fallback, guarded
            col_s[s + p] = (int)(lo & 0x7FFFFu); val_s[s + p] = (u16)(pk >> 32);
        }
    }
    __syncthreads();
    int m = n < BCAP ? n : BCAP;
    for (int i = tid; i < m; i += 512) {
        col_s[s + i] = (int)lcol[i];
        val_s[s + i] = lval[i];
    }
    // row_ptr: global CSR offsets for this bucket's rows (incl. N_NODES sentinel,
    // which lands at rl=120 of bucket 2040 since all real rows are < N_NODES).
    int rowbase = k * ROWS_PB;
    for (int i = tid; i < ROWS_PB; i += 512) {
        int r = rowbase + i;
        if (r <= N_NODES) row_ptr[r] = s + ex[i];
    }
}

// ---------------- SpMM: wave per row, lane = emb dim (proven) ----------------
__global__ void __launch_bounds__(256) k_spmm(
    const int* __restrict__ row_ptr, const int* __restrict__ col_s,
    const u16* __restrict__ val_s, const u16* __restrict__ ego_in,
    u16* __restrict__ ego_out, float* __restrict__ acc) {
    int row = __builtin_amdgcn_readfirstlane(
        (int)((blockIdx.x * blockDim.x + threadIdx.x) >> 6));
    int lane = threadIdx.x & 63;
    if (row >= N_NODES) return;
    int start = row_ptr[row];
    int end   = row_ptr[row + 1];
    float a = 0.f;
    int j = start;
    for (; j + 8 <= end; j += 8) {
        int c[8]; u16 w[8];
#pragma unroll
        for (int q = 0; q < 8; ++q) { c[q] = col_s[j + q]; w[q] = val_s[j + q]; }
        float x[8];
#pragma unroll
        for (int q = 0; q < 8; ++q) {
            u32 cc = (u32)c[q] & 0x7FFFFu;           // bounded gather
            x[q] = bf2f(ego_in[cc * EMB + lane]);
        }
#pragma unroll
        for (int q = 0; q < 8; ++q) a += bf2f(w[q]) * x[q];
    }
    for (; j < end; ++j) {
        u32 cc = (u32)col_s[j] & 0x7FFFFu;
        a += bf2f(val_s[j]) * bf2f(ego_in[cc * EMB + lane]);
    }
    int o = row * EMB + lane;
    acc[o] += a;
    ego_out[o] = f2bf(a);
}

// ---------------- T2 fallback: CSR by permutation ----------------
__global__ void k_hist(const int* __restrict__ rows, int* __restrict__ cnt) {
    int e = blockIdx.x * blockDim.x + threadIdx.x;
    if (e < NNZ) atomicAdd(&cnt[rows[e]], 1);
}

__global__ void k_scatter_perm(const int* __restrict__ rows, int* __restrict__ cursor,
                               u32* __restrict__ perm) {
    int e = blockIdx.x * blockDim.x + threadIdx.x;
    if (e >= NNZ) return;
    int r = rows[e];
    int p = atomicAdd(&cursor[r], 1);
    perm[p] = (u32)e;
}

__global__ void __launch_bounds__(256) k_spmm_perm(
    const int* __restrict__ row_ptr, const u32* __restrict__ perm,
    const int* __restrict__ cols, const void* __restrict__ vals,
    const int* __restrict__ flags, const u16* __restrict__ ego_in,
    u16* __restrict__ ego_out, float* __restrict__ acc) {
    int row = __builtin_amdgcn_readfirstlane(
        (int)((blockIdx.x * blockDim.x + threadIdx.x) >> 6));
    int lane = threadIdx.x & 63;
    if (row >= N_NODES) return;
    int valF32 = flags[1];
    int start = row_ptr[row];
    int end   = row_ptr[row + 1];
    float a = 0.f;
    for (int j = start; j < end; ++j) {
        u32 eid = perm[j];
        int c = cols[eid];
        float w = valF32 ? ((const float*)vals)[eid] : bf2f(((const u16*)vals)[eid]);
        a += w * bf2f(ego_in[c * EMB + lane]);
    }
    int o = row * EMB + lane;
    acc[o] += a;
    ego_out[o] = f2bf(a);
}

// ---------------- T3 fallback: edge-parallel atomics ----------------
__global__ void __launch_bounds__(256) k_edge_atomic(
    const int* __restrict__ rows, const int* __restrict__ cols,
    const void* __restrict__ vals, const int* __restrict__ flags,
    const u16* __restrict__ ego, float* __restrict__ layer) {
    int t = blockIdx.x * blockDim.x + threadIdx.x;
    int e = t >> 4;
    if (e >= NNZ) return;
    int d4 = (t & 15) * 4;
    int r = rows[e], c = cols[e];
    float w = flags[1] ? ((const float*)vals)[e] : bf2f(((const u16*)vals)[e]);
    ushort4 x = *(const ushort4*)(ego + c * EMB + d4);
    float* dst = layer + r * EMB + d4;
    atomicAdd(dst + 0, w * bf2f(x.x));
    atomicAdd(dst + 1, w * bf2f(x.y));
    atomicAdd(dst + 2, w * bf2f(x.z));
    atomicAdd(dst + 3, w * bf2f(x.w));
}

__global__ void k_layer_fin(float* __restrict__ layer, float* __restrict__ acc,
                            u16* __restrict__ ego) {
    int t = blockIdx.x * blockDim.x + threadIdx.x;
    int e = t * 4;
    if (e >= TOTAL_ELEMS) return;
    float4 L = *(const float4*)(layer + e);
    float4 A = *(const float4*)(acc + e);
    A.x += L.x; A.y += L.y; A.z += L.z; A.w += L.w;
    *(float4*)(acc + e) = A;
    ushort4 o;
    o.x = f2bf(L.x); o.y = f2bf(L.y); o.z = f2bf(L.z); o.w = f2bf(L.w);
    *(ushort4*)(ego + e) = o;
    float4 z; z.x = 0.f; z.y = 0.f; z.z = 0.f; z.w = 0.f;
    *(float4*)(layer + e) = z;
}

// ---------------- finalize: out = (acc / 4) in output dtype ----------------
__global__ void k_final(const float* __restrict__ acc, const int* __restrict__ flags,
                        void* __restrict__ out) {
    int t = blockIdx.x * blockDim.x + threadIdx.x;
    int e = t * 4;
    if (e >= TOTAL_ELEMS) return;
    float4 f = *(const float4*)(acc + e);
    f.x *= 0.25f; f.y *= 0.25f; f.z *= 0.25f; f.w *= 0.25f;
    if (flags[0]) {
        *(float4*)((float*)out + e) = f;
    } else {
        ushort4 v;
        v.x = f2bf(f.x); v.y = f2bf(f.y); v.z = f2bf(f.z); v.w = f2bf(f.w);
        *(ushort4*)((u16*)out + e) = v;
    }
}

extern "C" void kernel_launch(void* const* d_in, const int* in_sizes, int n_in,
                              void* d_out, int out_size, void* d_ws, size_t ws_size,
                              hipStream_t stream) {
    const void* user = d_in[0];
    const void* item = d_in[1];
    const void* vals = d_in[2];
    const int*  rows = (const int*)d_in[3];
    const int*  cols = (const int*)d_in[4];

    char* ws = (char*)d_ws;
    int* flags = (int*)ws;

    const int initGrid = (TOTAL_ELEMS / 4 + 255) / 256;   // 18750
    const int edgeGrid = (NNZ + 255) / 256;                // 50000
    const int spmmGrid = (N_NODES * 64) / 256;             // 75000

    k_detect<<<1, 64, 0, stream>>>((const u16*)user, (const u16*)vals, flags);

    if (ws_size >= T0_NEED) {
        // ---- T0: bucketed multisplit -> row sort (CSR + row_ptr) -> wave-per-row SpMM ----
        size_t off = FLAGS_SZ;
        int* cntm = (int*)(ws + off); off += CNTM_SZ;     // counts -> offsets (in place)
        int* bs2  = (int*)(ws + off); off += BS_SZ;
        int* bo2  = (int*)(ws + off); off += BS_SZ;
        int* col_s = (int*)(ws + off); off += COL_SZ;     // plain col (CSR order)
        u16* val_s = (u16*)(ws + off); off += VALSORT_SZ;
        int* row_ptr = (int*)(ws + off); off += RP_SZ;
        char* big  = ws + off;                            // 115.2MB shared region
        u64*   stg = (u64*)big;                           // staging (dead after k_bsort)
        float* acc = (float*)big;                         // live after k_init
        u16 *ego0, *ego1;
        bool outF32 = (out_size >= (int)(TOTAL_ELEMS * 4));
        if (outF32) {                                     // both egos fit in d_out
            ego0 = (u16*)d_out;
            ego1 = (u16*)d_out + TOTAL_ELEMS;
        } else {
            ego0 = (u16*)d_out;
            ego1 = (u16*)(big + ACC_SZ);
        }

        k_bhist<<<NB_A, 512, 0, stream>>>(rows, cntm);
        // k-major exclusive scan of the 2048 x 196 count matrix (in place)
        k_scan_reduce<16><<<98, 256, 0, stream>>>(cntm, bs2, CNT_LEN);
        k_scan_block<<<1, 256, 0, stream>>>(bs2, bo2, 98);
        k_scan_down<16><<<98, 256, 0, stream>>>(cntm, bo2, cntm, (int*)0, CNT_LEN, 0, 0);

        k_bscatter<<<NB_A, 512, 0, stream>>>(rows, cols, vals, flags, cntm, stg);
        k_bsort<<<NBUCK, 512, 0, stream>>>(cntm, stg, col_s, val_s, row_ptr);

        k_init<<<initGrid, 256, 0, stream>>>(user, item, flags, ego0, acc); // after k_bsort: acc aliases staging
        k_spmm<<<spmmGrid, 256, 0, stream>>>(row_ptr, col_s, val_s, ego0, ego1, acc);
        k_spmm<<<spmmGrid, 256, 0, stream>>>(row_ptr, col_s, val_s, ego1, ego0, acc);
        k_spmm<<<spmmGrid, 256, 0, stream>>>(row_ptr, col_s, val_s, ego0, ego1, acc);
        k_final<<<initGrid, 256, 0, stream>>>(acc, flags, d_out);
    } else if (ws_size >= T2_NEED) {
        // ---- T2: permutation CSR ----
        size_t off = FLAGS_SZ;
        float* acc = (float*)(ws + off); off += ACC_SZ;
        u16* ego0 = (u16*)d_out;
        u16* ego1 = (u16*)(ws + off); off += EGO_SZ;
        int* row_ptr = (int*)(ws + off); off += RP_SZ;
        int* cursor  = (int*)(ws + off); off += RP_SZ;
        int* bsums   = (int*)(ws + off); off += BS_SZ;
        int* boffs   = (int*)(ws + off); off += BS_SZ;
        u32* perm    = (u32*)(ws + off); off += PERM_SZ;

        hipMemsetAsync(cursor, 0, N_NODES * sizeof(int), stream);
        k_init<<<initGrid, 256, 0, stream>>>(user, item, flags, ego0, acc);
        k_hist<<<edgeGrid, 256, 0, stream>>>(rows, cursor);
        k_scan_reduce<8><<<147, 256, 0, stream>>>(cursor, bsums, N_NODES);
        k_scan_block<<<1, 256, 0, stream>>>(bsums, boffs, 147);
        k_scan_down<8><<<147, 256, 0, stream>>>(cursor, boffs, row_ptr, cursor,
                                                N_NODES, NNZ, 1);
        k_scatter_perm<<<edgeGrid, 256, 0, stream>>>(rows, cursor, perm);
        k_spmm_perm<<<spmmGrid, 256, 0, stream>>>(row_ptr, perm, cols, vals, flags,
                                                  ego0, ego1, acc);
        k_spmm_perm<<<spmmGrid, 256, 0, stream>>>(row_ptr, perm, cols, vals, flags,
                                                  ego1, ego0, acc);
        k_spmm_perm<<<spmmGrid, 256, 0, stream>>>(row_ptr, perm, cols, vals, flags,
                                                  ego0, ego1, acc);
        k_final<<<initGrid, 256, 0, stream>>>(acc, flags, d_out);
    } else {
        // ---- T3: edge-parallel atomics, minimal footprint ----
        size_t off = FLAGS_SZ;
        float* acc   = (float*)(ws + off); off += ACC_SZ;
        float* layer = (float*)(ws + off); off += LAYER_SZ;
        u16* ego = (u16*)d_out;
        hipMemsetAsync(layer, 0, LAYER_SZ, stream);
        k_init<<<initGrid, 256, 0, stream>>>(user, item, flags, ego, acc);
        const int atomGrid = (NNZ * 16) / 256;
        for (int l = 0; l < 3; ++l) {
            k_edge_atomic<<<atomGrid, 256, 0, stream>>>(rows, cols, vals, flags, ego, layer);
            k_layer_fin<<<initGrid, 256, 0, stream>>>(layer, acc, ego);
        }
        k_final<<<initGrid, 256, 0, stream>>>(acc, flags, d_out);
    }
}